// Round 10
// baseline (332.963 us; speedup 1.0000x reference)
//
#include <hip/hip_runtime.h>
#include <hip/hip_bf16.h>

// Problem constants (fixed by reference)
#define NCELLS 16384
#define DIM    768
#define NHEADS 8
#define DHEAD  96           // 768/8
#define MAXH   8
#define ND     (NCELLS * DIM)          // 12582912

// ALL float tensors are fp32 I/O. Internal compute: bf16 MFMA, fp32 accum.
// R9->R10: out-projection GEMM folded into fusion GEMM algebraically:
//   h = cwp@W1^T + ctx@Wc^T + bias',  Wc = W2@Wo,  bias' = fus_b + W2@out_b
// (one fewer GEMM dispatch + 50 MB less HBM round-trip).

using bf16 = __hip_bfloat16;
typedef short  short8  __attribute__((ext_vector_type(8)));
typedef short  short4v __attribute__((ext_vector_type(4)));
typedef float  floatx4 __attribute__((ext_vector_type(4)));

__device__ inline short f2b(float f) {
    bf16 h = __float2bfloat16(f);
    unsigned short u; __builtin_memcpy(&u, &h, 2); return (short)u;
}
__device__ inline float b2f(short u) {
    unsigned x = ((unsigned)(unsigned short)u) << 16;
    float f; __builtin_memcpy(&f, &x, 4); return f;
}

// load 8 consecutive fp32, convert to 8 bf16
__device__ inline short8 ld8(const float* p) {
    floatx4 a = *reinterpret_cast<const floatx4*>(p);
    floatx4 b = *reinterpret_cast<const floatx4*>(p + 4);
    short8 o;
#pragma unroll
    for (int i = 0; i < 4; ++i) { o[i] = f2b(a[i]); o[i + 4] = f2b(b[i]); }
    return o;
}

// async 16B global -> LDS (direct DMA, no VGPR round-trip).
__device__ __forceinline__ void cp16(const void* g, void* l) {
    __builtin_amdgcn_global_load_lds(
        (const __attribute__((address_space(1))) void*)g,
        (__attribute__((address_space(3))) void*)l, 16, 0, 0);
}

// ===========================================================================
// Pure-bf16 GEMM, 128x128 tile, BK=64, 256 thr (4 waves, 2x2), staging via
// global_load_lds width=16. XCD-swizzled linear grid: mb=id&127, nb=id>>7.
// LDS tiles UNPADDED [128][64]; bank conflicts broken by XOR-swizzling the
// k-group with row&7 on the GLOBAL source address + matching XOR on ds_read.
// Measured R7-R9: 0 bank conflicts, fusion (K=1536) ~54 us (~740 TF).
// DUAL=1: A spans K=1536 as [A | A2]. COUT: 0=f32 C, 1=bf16 C.
// ===========================================================================
template <int DUAL, int COUT>
__global__ __launch_bounds__(256) void gemm_bf(
    const bf16* __restrict__ A, const bf16* __restrict__ A2,
    const bf16* __restrict__ W, int ldw,
    const float* __restrict__ bias,
    float* __restrict__ Cf, bf16* __restrict__ Cb, int K)
{
    __shared__ short As[128 * 64];   // 16,384 B
    __shared__ short Bs[128 * 64];   // 16,384 B
    const int tid = threadIdx.x, wave = tid >> 6, lane = tid & 63;
    const int id = blockIdx.x;
    const int m0 = (id & 127) * 128;
    const int n0 = (id >> 7) * 128;
    const int wr = (wave & 1) * 64, wc = (wave >> 1) * 64;
    const int fr = lane & 15, kg = lane >> 4;   // fragment row / k-group

    const int srow = lane >> 3;            // row within chunk (== row&7)
    const int scol = (lane & 7) ^ srow;    // swizzled source k-group

    floatx4 acc[16];
#pragma unroll
    for (int i = 0; i < 16; ++i) acc[i] = (floatx4){0.f, 0.f, 0.f, 0.f};

    for (int k0 = 0; k0 < K; k0 += 64) {
        const bf16* Ak; int ka;
        if (!DUAL || k0 < DIM) { Ak = A;  ka = k0; }
        else                   { Ak = A2; ka = k0 - DIM; }

        __syncthreads();   // previous iteration's ds_reads complete
#pragma unroll
        for (int i = 0; i < 4; ++i) {
            const int c = i * 4 + wave;
            const int row = c * 8 + srow;
            cp16(Ak + (size_t)(m0 + row) * DIM + ka + scol * 8,
                 &As[c * 512 + lane * 8]);
            cp16(W  + (size_t)(n0 + row) * ldw + k0 + scol * 8,
                 &Bs[c * 512 + lane * 8]);
        }
        __syncthreads();   // vmcnt(0) drained: tiles landed

#pragma unroll
        for (int kk = 0; kk < 2; ++kk) {
            short8 af[4], bfv[4];
#pragma unroll
            for (int i = 0; i < 4; ++i) {
                const int sa = ((kk * 4 + kg) ^ (fr & 7)) * 8;
                af[i]  = *reinterpret_cast<const short8*>(&As[(wr + i * 16 + fr) * 64 + sa]);
                bfv[i] = *reinterpret_cast<const short8*>(&Bs[(wc + i * 16 + fr) * 64 + sa]);
            }
#pragma unroll
            for (int i = 0; i < 4; ++i)
#pragma unroll
                for (int j = 0; j < 4; ++j)
                    acc[i * 4 + j] = __builtin_amdgcn_mfma_f32_16x16x32_bf16(
                        af[i], bfv[j], acc[i * 4 + j], 0, 0, 0);
        }
    }

    const int col_l = lane & 15, row_q = kg * 4;
#pragma unroll
    for (int j = 0; j < 4; ++j) {
        const int col = n0 + wc + j * 16 + col_l;
        const float bv = bias[col];
#pragma unroll
        for (int i = 0; i < 4; ++i) {
#pragma unroll
            for (int r = 0; r < 4; ++r) {
                const int row = m0 + wr + i * 16 + row_q + r;
                const float v = acc[i * 4 + j][r] + bv;
                if (COUT == 0) Cf[(size_t)row * DIM + col] = v;
                else           Cb[(size_t)row * DIM + col] = __float2bfloat16(v);
            }
        }
    }
}

// ===========================================================================
// PREP kernel: one dispatch, block-uniform role ranges:
//   [0, 6144)        cwp_b  = bf16(ce + re[pr] + co[pc])     (thread = 8 elems)
//   [6144, 6720)     Wq_b   = bf16(in_proj_w[0:768x768])     (thread = 4 elems)
//   [6720, 7296)     W_cat[:, 0:768]  = bf16(fus_w[:, 0:768])
//   [7296, 7488)     HKV    = hdr @ [Wk;Wv]^T + bias  (64x64 MFMA GEMM)
//   [7488, 7632)     W_cat[:, 768:]   = Wc = W2 @ Wo  (64x64 MFMA GEMM,
//                     A = fus_w[:,768:] row-contig; B staged TRANSPOSED from Wo)
//   [7632]           bias' = fus_b + W2 @ out_b       (single block)
// ===========================================================================
__global__ __launch_bounds__(256) void prep_kernel(
    const float* __restrict__ ce, const int* __restrict__ pos,
    const float* __restrict__ re, const float* __restrict__ co,
    bf16* __restrict__ cwp_b,
    const float* __restrict__ in_proj_w, bf16* __restrict__ Wq_b,
    const float* __restrict__ fus_w,     bf16* __restrict__ W_cat,
    const float* __restrict__ out_w,     const float* __restrict__ out_b,
    const float* __restrict__ fus_b,     float* __restrict__ biasp,
    const float* __restrict__ hdr, const float* __restrict__ in_proj_b,
    bf16* __restrict__ HKV)
{
    __shared__ short As[64 * 40];   // MFMA branches only (10,240 B)
    __shared__ short Bs[64 * 40];
    const int b = blockIdx.x, tid = threadIdx.x;

    if (b < 6144) {                          // ---- cwp_b ----
        const int gid  = b * 256 + tid;
        const int cell = gid / 96;
        const int off  = (gid % 96) * 8;
        int pr = pos[cell * 2 + 0]; pr = min(max(pr, 0), 99);
        int pc = pos[cell * 2 + 1]; pc = min(max(pc, 0), 99);
        const float* a = ce + (size_t)cell * DIM + off;
        const float* bb = re + (size_t)pr * DIM + off;
        const float* c = co + (size_t)pc * DIM + off;
        floatx4 a0 = *reinterpret_cast<const floatx4*>(a);
        floatx4 a1 = *reinterpret_cast<const floatx4*>(a + 4);
        floatx4 b0 = *reinterpret_cast<const floatx4*>(bb);
        floatx4 b1 = *reinterpret_cast<const floatx4*>(bb + 4);
        floatx4 c0 = *reinterpret_cast<const floatx4*>(c);
        floatx4 c1 = *reinterpret_cast<const floatx4*>(c + 4);
        short8 o;
#pragma unroll
        for (int i = 0; i < 4; ++i) {
            o[i]     = f2b(a0[i] + b0[i] + c0[i]);
            o[i + 4] = f2b(a1[i] + b1[i] + c1[i]);
        }
        *reinterpret_cast<short8*>((short*)cwp_b + (size_t)cell * DIM + off) = o;
    } else if (b < 6720) {                   // ---- Wq_b cvt ----
        const int i = (b - 6144) * 256 + tid;           // 4-elem chunk idx
        floatx4 v = *reinterpret_cast<const floatx4*>(in_proj_w + (size_t)i * 4);
        short4v o;
#pragma unroll
        for (int j = 0; j < 4; ++j) o[j] = f2b(v[j]);
        *reinterpret_cast<short4v*>((short*)Wq_b + (size_t)i * 4) = o;
    } else if (b < 7296) {                   // ---- W_cat[:, 0:768] cvt ----
        const int i = (b - 6720) * 256 + tid;           // chunk of 4 within row
        const int n = i / 192, j = (i % 192) * 4;       // 192 chunks per row
        floatx4 v = *reinterpret_cast<const floatx4*>(fus_w + (size_t)n * 1536 + j);
        short4v o;
#pragma unroll
        for (int e = 0; e < 4; ++e) o[e] = f2b(v[e]);
        *reinterpret_cast<short4v*>((short*)W_cat + (size_t)n * 1536 + j) = o;
    } else if (b < 7488) {                   // ---- HKV GEMM ----
        const int b2 = b - 7296;
        const int m0 = (b2 & 7) * 64, n0 = (b2 >> 3) * 64;
        const float* W = in_proj_w + (size_t)DIM * DIM;   // [Wk;Wv]
        const float* bias = in_proj_b + DIM;
        const int wave = tid >> 6, lane = tid & 63;
        const int lr = tid >> 2, lc = (tid & 3) * 8;
        const int fr = lane & 15, fk = (lane >> 4) * 8;

        floatx4 acc[4];
#pragma unroll
        for (int i = 0; i < 4; ++i) acc[i] = (floatx4){0.f, 0.f, 0.f, 0.f};
        for (int k0 = 0; k0 < DIM; k0 += 32) {
            short8 av = ld8(hdr + (size_t)(m0 + lr) * DIM + k0 + lc);
            short8 wv = ld8(W   + (size_t)(n0 + lr) * DIM + k0 + lc);
            __syncthreads();
            *reinterpret_cast<short8*>(&As[lr * 40 + lc]) = av;
            *reinterpret_cast<short8*>(&Bs[lr * 40 + lc]) = wv;
            __syncthreads();
            short8 af = *reinterpret_cast<const short8*>(&As[(wave * 16 + fr) * 40 + fk]);
#pragma unroll
            for (int t = 0; t < 4; ++t) {
                short8 bfv = *reinterpret_cast<const short8*>(&Bs[(t * 16 + fr) * 40 + fk]);
                acc[t] = __builtin_amdgcn_mfma_f32_16x16x32_bf16(af, bfv, acc[t], 0, 0, 0);
            }
        }
        const int col_l = lane & 15, row_q = (lane >> 4) * 4;
#pragma unroll
        for (int t = 0; t < 4; ++t) {
            const int col = n0 + t * 16 + col_l;
            const float bv = bias[col];
#pragma unroll
            for (int r = 0; r < 4; ++r) {
                const int row = m0 + wave * 16 + row_q + r;
                HKV[(size_t)row * 1536 + col] = __float2bfloat16(acc[t][r] + bv);
            }
        }
    } else if (b < 7632) {                   // ---- Wc = W2 @ Wo GEMM ----
        // C[n,j] = sum_k fus_w[n,768+k] * out_w[k,j]; 64x64 tiles, 12x12 grid.
        const int b2 = b - 7488;
        const int n0 = (b2 % 12) * 64, j0 = (b2 / 12) * 64;
        const int wave = tid >> 6, lane = tid & 63;
        const int lr = tid >> 2, lc = (tid & 3) * 8;
        const int fr = lane & 15, fk = (lane >> 4) * 8;

        floatx4 acc[4];
#pragma unroll
        for (int i = 0; i < 4; ++i) acc[i] = (floatx4){0.f, 0.f, 0.f, 0.f};
        for (int k0 = 0; k0 < DIM; k0 += 32) {
            // A: rows n (contig k)
            short8 av = ld8(fus_w + (size_t)(n0 + lr) * 1536 + DIM + k0 + lc);
            // B staged transposed: Bs[j_row][k] = Wo[k0+k, j0+j_row]
            float tmp[8];
#pragma unroll
            for (int i = 0; i < 8; ++i)
                tmp[i] = out_w[(size_t)(k0 + lc + i) * DIM + j0 + lr];
            short8 wv;
#pragma unroll
            for (int i = 0; i < 8; ++i) wv[i] = f2b(tmp[i]);
            __syncthreads();
            *reinterpret_cast<short8*>(&As[lr * 40 + lc]) = av;
            *reinterpret_cast<short8*>(&Bs[lr * 40 + lc]) = wv;
            __syncthreads();
            short8 af = *reinterpret_cast<const short8*>(&As[(wave * 16 + fr) * 40 + fk]);
#pragma unroll
            for (int t = 0; t < 4; ++t) {
                short8 bfv = *reinterpret_cast<const short8*>(&Bs[(t * 16 + fr) * 40 + fk]);
                acc[t] = __builtin_amdgcn_mfma_f32_16x16x32_bf16(af, bfv, acc[t], 0, 0, 0);
            }
        }
        const int col_l = lane & 15, row_q = (lane >> 4) * 4;
#pragma unroll
        for (int t = 0; t < 4; ++t) {
            const int j = j0 + t * 16 + col_l;
#pragma unroll
            for (int r = 0; r < 4; ++r) {
                const int n = n0 + wave * 16 + row_q + r;
                W_cat[(size_t)n * 1536 + DIM + j] = __float2bfloat16(acc[t][r]);
            }
        }
    } else {                                 // ---- bias' (1 block) ----
#pragma unroll
        for (int rr = 0; rr < 3; ++rr) {
            const int n = tid + rr * 256;
            float s = fus_b[n];
            const float* wrow = fus_w + (size_t)n * 1536 + DIM;
            for (int k = 0; k < DIM; k += 4) {
                floatx4 wv = *reinterpret_cast<const floatx4*>(wrow + k);
                floatx4 bv = *reinterpret_cast<const floatx4*>(out_b + k);
                s += wv[0]*bv[0] + wv[1]*bv[1] + wv[2]*bv[2] + wv[3]*bv[3];
            }
            biasp[n] = s;
        }
    }
}

// ---------------------------------------------------------------------------
// Vectorized attention, 2 cells per 256-thr block (half-block per cell).
// All q/HKV/ctx traffic as short8 (16 B). ctx -> ws (bf16).
// ---------------------------------------------------------------------------
__global__ __launch_bounds__(256) void attn_v_kernel(
    const bf16* __restrict__ q, bf16* __restrict__ ctx,
    const bf16* __restrict__ HKV, const int* __restrict__ map,
    float* __restrict__ wout)
{
    const int h = threadIdx.x >> 7;           // half-block 0/1
    const int t = threadIdx.x & 127;          // lane within half
    const int cell = blockIdx.x * 2 + h;
    __shared__ float qs[2][DIM];
    __shared__ float sc[2][64];
    __shared__ float at[2][64];
    __shared__ int   ids[2][MAXH];
    __shared__ float msk[2][MAXH];

    if (t < MAXH) {
        int id = map[cell * MAXH + t];
        msk[h][t] = (id >= 0) ? 1.f : 0.f;
        ids[h][t] = (id >= 0) ? id : 0;
    }
    if (t < 96) {  // stage q: 96 x short8
        short8 qv = *reinterpret_cast<const short8*>((const short*)q + (size_t)cell * DIM + t * 8);
#pragma unroll
        for (int e = 0; e < 8; ++e) qs[h][t * 8 + e] = b2f(qv[e]);
    }
    __syncthreads();

    if (t < 64) {  // scores: head a = t>>3, slot j = t&7
        const int a = t >> 3, j = t & 7;
        const short* kp = (const short*)HKV + (size_t)ids[h][j] * 1536 + a * DHEAD;
        float s = 0.f;
#pragma unroll
        for (int c = 0; c < 12; ++c) {
            short8 kv = *reinterpret_cast<const short8*>(kp + c * 8);
#pragma unroll
            for (int e = 0; e < 8; ++e)
                s += qs[h][a * DHEAD + c * 8 + e] * b2f(kv[e]);
        }
        s *= 0.10206207261596577f;  // 1/sqrt(96)
        sc[h][t] = (msk[h][j] != 0.f) ? s : -1e9f;
    }
    __syncthreads();

    if (t < NHEADS) {  // softmax per head
        float m = -3e38f;
        for (int j = 0; j < MAXH; ++j) m = fmaxf(m, sc[h][t * 8 + j]);
        float e[MAXH]; float sum = 0.f;
        for (int j = 0; j < MAXH; ++j) { e[j] = expf(sc[h][t * 8 + j] - m); sum += e[j]; }
        const float inv = 1.f / sum;
        for (int j = 0; j < MAXH; ++j)
            at[h][t * 8 + j] = (msk[h][j] != 0.f) ? e[j] * inv : 0.f;
    }
    __syncthreads();

    if (t < MAXH) {  // head-averaged weights
        float s = 0.f;
        for (int a = 0; a < NHEADS; ++a) s += at[h][a * 8 + t];
        wout[(size_t)cell * MAXH + t] = s * 0.125f;
    }

    if (t < 96) {  // ctx: dims [t*8, t*8+8), head a = t/12
        const int a = t / 12, d0 = t * 8;
        float acc[8];
#pragma unroll
        for (int e = 0; e < 8; ++e) acc[e] = 0.f;
#pragma unroll
        for (int j = 0; j < MAXH; ++j) {
            short8 vv = *reinterpret_cast<const short8*>(
                (const short*)HKV + (size_t)ids[h][j] * 1536 + DIM + d0);
            const float w = at[h][a * 8 + j];
#pragma unroll
            for (int e = 0; e < 8; ++e) acc[e] += w * b2f(vv[e]);
        }
        short8 o;
#pragma unroll
        for (int e = 0; e < 8; ++e) o[e] = f2b(acc[e]);
        *reinterpret_cast<short8*>((short*)ctx + (size_t)cell * DIM + d0) = o;
    }
}

// ---------------------------------------------------------------------------
// LayerNorm + ReLU + has-select, IN-PLACE, vectorized; 2 cells per 384-thr
// block (three waves per cell; halves wave-aligned: 192 = 3 x 64).
// ---------------------------------------------------------------------------
__global__ __launch_bounds__(384) void ln_v_kernel(
    float* io, const int* __restrict__ map,
    const float* __restrict__ ce, const int* __restrict__ pos,
    const float* __restrict__ re, const float* __restrict__ co,
    const float* __restrict__ g, const float* __restrict__ b)
{
    const int h = threadIdx.x / 192;          // half 0/1
    const int t = threadIdx.x % 192;
    const int cell = blockIdx.x * 2 + h;
    const int wave = t >> 6, lane = t & 63;
    __shared__ float ws_[2][3], wq_[2][3];
    __shared__ int hasf[2];
    if (threadIdx.x < 2) hasf[threadIdx.x] = 0;

    float* hp = io + (size_t)cell * DIM;
    floatx4 v = *reinterpret_cast<const floatx4*>(hp + t * 4);
    float s  = v[0] + v[1] + v[2] + v[3];
    float q2 = v[0]*v[0] + v[1]*v[1] + v[2]*v[2] + v[3]*v[3];
#pragma unroll
    for (int off = 32; off > 0; off >>= 1) {
        s  += __shfl_down(s, off);
        q2 += __shfl_down(q2, off);
    }
    __syncthreads();           // hasf init visible
    if (t < MAXH && map[cell * MAXH + t] >= 0) hasf[h] = 1;
    if (lane == 0) { ws_[h][wave] = s; wq_[h][wave] = q2; }
    __syncthreads();

    const float mu  = (ws_[h][0] + ws_[h][1] + ws_[h][2]) * (1.f / 768.f);
    const float var = (wq_[h][0] + wq_[h][1] + wq_[h][2]) * (1.f / 768.f) - mu * mu;
    const float inv = rsqrtf(var + 1e-5f);

    if (hasf[h]) {
        floatx4 gv = *reinterpret_cast<const floatx4*>(g + t * 4);
        floatx4 bv = *reinterpret_cast<const floatx4*>(b + t * 4);
        floatx4 o;
#pragma unroll
        for (int e = 0; e < 4; ++e)
            o[e] = fmaxf((v[e] - mu) * inv * gv[e] + bv[e], 0.f);
        *reinterpret_cast<floatx4*>(hp + t * 4) = o;
    } else {
        int pr = pos[cell * 2 + 0]; pr = min(max(pr, 0), 99);
        int pc = pos[cell * 2 + 1]; pc = min(max(pc, 0), 99);
        floatx4 a0 = *reinterpret_cast<const floatx4*>(ce + (size_t)cell * DIM + t * 4);
        floatx4 b0 = *reinterpret_cast<const floatx4*>(re + (size_t)pr * DIM + t * 4);
        floatx4 c0 = *reinterpret_cast<const floatx4*>(co + (size_t)pc * DIM + t * 4);
        floatx4 o;
#pragma unroll
        for (int e = 0; e < 4; ++e) o[e] = a0[e] + b0[e] + c0[e];
        *reinterpret_cast<floatx4*>(hp + t * 4) = o;
    }
}

// ---------------------------------------------------------------------------
extern "C" void kernel_launch(void* const* d_in, const int* in_sizes, int n_in,
                              void* d_out, int out_size, void* d_ws, size_t ws_size,
                              hipStream_t stream) {
    (void)in_sizes; (void)n_in; (void)out_size; (void)ws_size;

    const float* cell_emb  = (const float*)d_in[0];
    const float* hdr_emb   = (const float*)d_in[1];
    const int*   map       = (const int*)d_in[2];
    const int*   pos       = (const int*)d_in[3];
    const float* in_proj_w = (const float*)d_in[4];   // [2304, 768]
    const float* in_proj_b = (const float*)d_in[5];
    const float* out_w     = (const float*)d_in[6];   // [768, 768]
    const float* out_b     = (const float*)d_in[7];
    const float* row_emb   = (const float*)d_in[8];
    const float* col_emb   = (const float*)d_in[9];
    const float* fus_w     = (const float*)d_in[10];  // [768, 1536]
    const float* fus_b     = (const float*)d_in[11];
    const float* ln_g      = (const float*)d_in[12];
    const float* ln_b      = (const float*)d_in[13];
    float* out = (float*)d_out;

    // ws layout (bytes) — total 55,446,528 + 3072 (proven ws >= 56.6 MB, R6-R9):
    //   HKV   bf16 [512,1536]  @ 0          ( 1,572,864)
    //   ctx_b bf16 [16384,768] @ 1572864    (25,165,824)
    //   cwp_b bf16 [16384,768] @ 26738688   (25,165,824)
    //   Wq_b  bf16 [768,768]   @ 51904512   ( 1,179,648)
    //   W_cat bf16 [768,1536]  @ 53084160   ( 2,359,296)  = [W1 | Wc]
    //   biasp f32  [768]       @ 55443456   (      3,072)
    char* ws = (char*)d_ws;
    bf16*  HKV   = (bf16*)ws;
    bf16*  ctx_b = (bf16*)(ws + 1572864);
    bf16*  cwp_b = (bf16*)(ws + 26738688);
    bf16*  Wq_b  = (bf16*)(ws + 51904512);
    bf16*  W_cat = (bf16*)(ws + 53084160);
    float* biasp = (float*)(ws + 55443456);
    // d_out raw-byte scratch: q_b bf16 @ [0, 25165824)  (dead before fusion)
    bf16*  q_b   = (bf16*)d_out;

    // 1. PREP: cwp_b, Wq_b, W_cat(=[bf16(W1) | W2@Wo]), HKV, bias' (one dispatch)
    prep_kernel<<<7633, 256, 0, stream>>>(
        cell_emb, pos, row_emb, col_emb, cwp_b,
        in_proj_w, Wq_b, fus_w, W_cat, out_w, out_b, fus_b, biasp,
        hdr_emb, in_proj_b, HKV);

    // 2. q_b = cwp_b @ Wq_b^T + bq  (bf16 out -> d_out bytes [0,25MB))
    gemm_bf<0, 1><<<768, 256, 0, stream>>>(
        cwp_b, nullptr, Wq_b, DIM, in_proj_b, nullptr, q_b, DIM);

    // 3. attention: q_b -> ctx_b (ws); weights -> d_out tail (fp32)
    attn_v_kernel<<<NCELLS / 2, 256, 0, stream>>>(q_b, ctx_b, HKV, map, out + ND);

    // 4. h = [cwp_b | ctx_b] @ W_cat^T + bias'  (fp32 -> d_out; q_b dead)
    //    (o-projection folded into W_cat's second half and bias')
    gemm_bf<1, 0><<<768, 256, 0, stream>>>(
        cwp_b, ctx_b, W_cat, 1536, biasp, out, nullptr, 1536);

    // 5. LayerNorm + ReLU + select (in-place on d_out fp32)
    ln_v_kernel<<<NCELLS / 2, 384, 0, stream>>>(out, map, cell_emb, pos,
                                                row_emb, col_emb, ln_g, ln_b);
}

// Round 11
// 321.025 us; speedup vs baseline: 1.0372x; 1.0372x over previous
//
#include <hip/hip_runtime.h>
#include <hip/hip_bf16.h>

// Problem constants (fixed by reference)
#define NCELLS 16384
#define DIM    768
#define NHEADS 8
#define DHEAD  96           // 768/8
#define MAXH   8
#define ND     (NCELLS * DIM)          // 12582912

// ALL float tensors are fp32 I/O. Internal compute: bf16 MFMA, fp32 accum.
// Out-projection folded into fusion GEMM:
//   h = cwp@W1^T + ctx@Wc^T + bias',  Wc = W2@Wo,  bias' = fus_b + W2@out_b

using bf16 = __hip_bfloat16;
typedef short  short8  __attribute__((ext_vector_type(8)));
typedef short  short4v __attribute__((ext_vector_type(4)));
typedef float  floatx4 __attribute__((ext_vector_type(4)));

__device__ inline short f2b(float f) {
    bf16 h = __float2bfloat16(f);
    unsigned short u; __builtin_memcpy(&u, &h, 2); return (short)u;
}
__device__ inline float b2f(short u) {
    unsigned x = ((unsigned)(unsigned short)u) << 16;
    float f; __builtin_memcpy(&f, &x, 4); return f;
}

// load 8 consecutive fp32, convert to 8 bf16
__device__ inline short8 ld8(const float* p) {
    floatx4 a = *reinterpret_cast<const floatx4*>(p);
    floatx4 b = *reinterpret_cast<const floatx4*>(p + 4);
    short8 o;
#pragma unroll
    for (int i = 0; i < 4; ++i) { o[i] = f2b(a[i]); o[i + 4] = f2b(b[i]); }
    return o;
}

// async 16B global -> LDS (direct DMA, no VGPR round-trip).
__device__ __forceinline__ void cp16(const void* g, void* l) {
    __builtin_amdgcn_global_load_lds(
        (const __attribute__((address_space(1))) void*)g,
        (__attribute__((address_space(3))) void*)l, 16, 0, 0);
}

// ===========================================================================
// Pure-bf16 GEMM, 128x128 tile, BK=64, 256 thr (4 waves, 2x2), staging via
// global_load_lds width=16. XCD-swizzled linear grid: mb=id&127, nb=id>>7.
// LDS tiles UNPADDED [128][64]; bank conflicts broken by XOR-swizzling the
// k-group with row&7 on the GLOBAL source address + matching XOR on ds_read.
// Measured R7-R9: 0 bank conflicts, fusion (K=1536) ~54 us (~740 TF).
// DUAL=1: A spans K=1536 as [A | A2]. COUT: 0=f32 C, 1=bf16 C.
// ===========================================================================
template <int DUAL, int COUT>
__global__ __launch_bounds__(256) void gemm_bf(
    const bf16* __restrict__ A, const bf16* __restrict__ A2,
    const bf16* __restrict__ W, int ldw,
    const float* __restrict__ bias,
    float* __restrict__ Cf, bf16* __restrict__ Cb, int K)
{
    __shared__ short As[128 * 64];   // 16,384 B
    __shared__ short Bs[128 * 64];   // 16,384 B
    const int tid = threadIdx.x, wave = tid >> 6, lane = tid & 63;
    const int id = blockIdx.x;
    const int m0 = (id & 127) * 128;
    const int n0 = (id >> 7) * 128;
    const int wr = (wave & 1) * 64, wc = (wave >> 1) * 64;
    const int fr = lane & 15, kg = lane >> 4;   // fragment row / k-group

    const int srow = lane >> 3;            // row within chunk (== row&7)
    const int scol = (lane & 7) ^ srow;    // swizzled source k-group

    floatx4 acc[16];
#pragma unroll
    for (int i = 0; i < 16; ++i) acc[i] = (floatx4){0.f, 0.f, 0.f, 0.f};

    for (int k0 = 0; k0 < K; k0 += 64) {
        const bf16* Ak; int ka;
        if (!DUAL || k0 < DIM) { Ak = A;  ka = k0; }
        else                   { Ak = A2; ka = k0 - DIM; }

        __syncthreads();   // previous iteration's ds_reads complete
#pragma unroll
        for (int i = 0; i < 4; ++i) {
            const int c = i * 4 + wave;
            const int row = c * 8 + srow;
            cp16(Ak + (size_t)(m0 + row) * DIM + ka + scol * 8,
                 &As[c * 512 + lane * 8]);
            cp16(W  + (size_t)(n0 + row) * ldw + k0 + scol * 8,
                 &Bs[c * 512 + lane * 8]);
        }
        __syncthreads();   // vmcnt(0) drained: tiles landed

#pragma unroll
        for (int kk = 0; kk < 2; ++kk) {
            short8 af[4], bfv[4];
#pragma unroll
            for (int i = 0; i < 4; ++i) {
                const int sa = ((kk * 4 + kg) ^ (fr & 7)) * 8;
                af[i]  = *reinterpret_cast<const short8*>(&As[(wr + i * 16 + fr) * 64 + sa]);
                bfv[i] = *reinterpret_cast<const short8*>(&Bs[(wc + i * 16 + fr) * 64 + sa]);
            }
#pragma unroll
            for (int i = 0; i < 4; ++i)
#pragma unroll
                for (int j = 0; j < 4; ++j)
                    acc[i * 4 + j] = __builtin_amdgcn_mfma_f32_16x16x32_bf16(
                        af[i], bfv[j], acc[i * 4 + j], 0, 0, 0);
        }
    }

    const int col_l = lane & 15, row_q = kg * 4;
#pragma unroll
    for (int j = 0; j < 4; ++j) {
        const int col = n0 + wc + j * 16 + col_l;
        const float bv = bias[col];
#pragma unroll
        for (int i = 0; i < 4; ++i) {
#pragma unroll
            for (int r = 0; r < 4; ++r) {
                const int row = m0 + wr + i * 16 + row_q + r;
                const float v = acc[i * 4 + j][r] + bv;
                if (COUT == 0) Cf[(size_t)row * DIM + col] = v;
                else           Cb[(size_t)row * DIM + col] = __float2bfloat16(v);
            }
        }
    }
}

// ===========================================================================
// PREP kernel: one dispatch, block-uniform role ranges. SLOW BLOCKS FIRST so
// they start at t=0 and overlap the fast elementwise blocks (R10 post-mortem:
// trailing slow blocks ran nearly alone -> 106 us prep).
//   [0, 144)         Wc = W2 @ Wo      (64x64 MFMA GEMM, coalesced Wo rows +
//                                       LDS transpose into Bs[j][k])
//   [144]            bias' = fus_b + W2 @ out_b   (single block)
//   [145, 6289)      cwp_b  = bf16(ce + re[pr] + co[pc])   (thread = 8 elems)
//   [6289, 6865)     Wq_b   = bf16(in_proj_w[0:768x768])   (thread = 4 elems)
//   [6865, 7441)     W_cat[:, 0:768] = bf16(fus_w[:, 0:768])
//   [7441, 7633)     HKV    = hdr @ [Wk;Wv]^T + bias  (64x64 MFMA GEMM)
// ===========================================================================
__global__ __launch_bounds__(256) void prep_kernel(
    const float* __restrict__ ce, const int* __restrict__ pos,
    const float* __restrict__ re, const float* __restrict__ co,
    bf16* __restrict__ cwp_b,
    const float* __restrict__ in_proj_w, bf16* __restrict__ Wq_b,
    const float* __restrict__ fus_w,     bf16* __restrict__ W_cat,
    const float* __restrict__ out_w,     const float* __restrict__ out_b,
    const float* __restrict__ fus_b,     float* __restrict__ biasp,
    const float* __restrict__ hdr, const float* __restrict__ in_proj_b,
    bf16* __restrict__ HKV)
{
    __shared__ short As[64 * 40];   // MFMA branches only (10,240 B)
    __shared__ short Bs[64 * 40];
    const int b = blockIdx.x, tid = threadIdx.x;

    if (b < 144) {                           // ---- Wc = W2 @ Wo ----
        // C[n][j] = sum_k W2[n][k] * Wo[k][j]; W2 = fus_w[:,768:] (contig k),
        // Wo rows contig in j. Tile 64n x 64j, BK=32.
        const int n0 = (b % 12) * 64, j0 = (b / 12) * 64;
        const int wave = tid >> 6, lane = tid & 63;
        const int lr = tid >> 2, lc = (tid & 3) * 8;      // A staging
        const int kk = tid >> 3, jj = (tid & 7) * 8;      // B staging (coalesced)
        const int fr = lane & 15, fk = (lane >> 4) * 8;

        floatx4 acc[4];
#pragma unroll
        for (int i = 0; i < 4; ++i) acc[i] = (floatx4){0.f, 0.f, 0.f, 0.f};
        for (int k0 = 0; k0 < DIM; k0 += 32) {
            // A: W2 rows, contiguous k -> coalesced
            short8 av = ld8(fus_w + (size_t)(n0 + lr) * 1536 + DIM + k0 + lc);
            // B: Wo row (k0+kk), 8 contiguous j -> coalesced float4 x2
            floatx4 w0 = *reinterpret_cast<const floatx4*>(out_w + (size_t)(k0 + kk) * DIM + j0 + jj);
            floatx4 w1 = *reinterpret_cast<const floatx4*>(out_w + (size_t)(k0 + kk) * DIM + j0 + jj + 4);
            __syncthreads();
            *reinterpret_cast<short8*>(&As[lr * 40 + lc]) = av;
            // transpose in LDS: Bs[j][k] (8 scalar writes)
#pragma unroll
            for (int e = 0; e < 4; ++e) {
                Bs[(jj + e) * 40 + kk]     = f2b(w0[e]);
                Bs[(jj + 4 + e) * 40 + kk] = f2b(w1[e]);
            }
            __syncthreads();
            short8 af = *reinterpret_cast<const short8*>(&As[(wave * 16 + fr) * 40 + fk]);
#pragma unroll
            for (int t = 0; t < 4; ++t) {
                short8 bfv = *reinterpret_cast<const short8*>(&Bs[(t * 16 + fr) * 40 + fk]);
                acc[t] = __builtin_amdgcn_mfma_f32_16x16x32_bf16(af, bfv, acc[t], 0, 0, 0);
            }
        }
        const int col_l = lane & 15, row_q = (lane >> 4) * 4;
#pragma unroll
        for (int t = 0; t < 4; ++t) {
            const int j = j0 + t * 16 + col_l;
#pragma unroll
            for (int r = 0; r < 4; ++r) {
                const int n = n0 + wave * 16 + row_q + r;
                W_cat[(size_t)n * 1536 + DIM + j] = __float2bfloat16(acc[t][r]);
            }
        }
    } else if (b == 144) {                   // ---- bias' ----
#pragma unroll
        for (int rr = 0; rr < 3; ++rr) {
            const int n = tid + rr * 256;
            float s = fus_b[n];
            const float* wrow = fus_w + (size_t)n * 1536 + DIM;
            for (int k = 0; k < DIM; k += 4) {
                floatx4 wv = *reinterpret_cast<const floatx4*>(wrow + k);
                floatx4 bv = *reinterpret_cast<const floatx4*>(out_b + k);
                s += wv[0]*bv[0] + wv[1]*bv[1] + wv[2]*bv[2] + wv[3]*bv[3];
            }
            biasp[n] = s;
        }
    } else if (b < 6289) {                   // ---- cwp_b ----
        const int gid  = (b - 145) * 256 + tid;
        const int cell = gid / 96;
        const int off  = (gid % 96) * 8;
        int pr = pos[cell * 2 + 0]; pr = min(max(pr, 0), 99);
        int pc = pos[cell * 2 + 1]; pc = min(max(pc, 0), 99);
        const float* a = ce + (size_t)cell * DIM + off;
        const float* bb = re + (size_t)pr * DIM + off;
        const float* c = co + (size_t)pc * DIM + off;
        floatx4 a0 = *reinterpret_cast<const floatx4*>(a);
        floatx4 a1 = *reinterpret_cast<const floatx4*>(a + 4);
        floatx4 b0 = *reinterpret_cast<const floatx4*>(bb);
        floatx4 b1 = *reinterpret_cast<const floatx4*>(bb + 4);
        floatx4 c0 = *reinterpret_cast<const floatx4*>(c);
        floatx4 c1 = *reinterpret_cast<const floatx4*>(c + 4);
        short8 o;
#pragma unroll
        for (int i = 0; i < 4; ++i) {
            o[i]     = f2b(a0[i] + b0[i] + c0[i]);
            o[i + 4] = f2b(a1[i] + b1[i] + c1[i]);
        }
        *reinterpret_cast<short8*>((short*)cwp_b + (size_t)cell * DIM + off) = o;
    } else if (b < 6865) {                   // ---- Wq_b cvt ----
        const int i = (b - 6289) * 256 + tid;
        floatx4 v = *reinterpret_cast<const floatx4*>(in_proj_w + (size_t)i * 4);
        short4v o;
#pragma unroll
        for (int j = 0; j < 4; ++j) o[j] = f2b(v[j]);
        *reinterpret_cast<short4v*>((short*)Wq_b + (size_t)i * 4) = o;
    } else if (b < 7441) {                   // ---- W_cat[:, 0:768] cvt ----
        const int i = (b - 6865) * 256 + tid;
        const int n = i / 192, j = (i % 192) * 4;
        floatx4 v = *reinterpret_cast<const floatx4*>(fus_w + (size_t)n * 1536 + j);
        short4v o;
#pragma unroll
        for (int e = 0; e < 4; ++e) o[e] = f2b(v[e]);
        *reinterpret_cast<short4v*>((short*)W_cat + (size_t)n * 1536 + j) = o;
    } else {                                 // ---- HKV GEMM ----
        const int b2 = b - 7441;
        const int m0 = (b2 & 7) * 64, n0 = (b2 >> 3) * 64;
        const float* W = in_proj_w + (size_t)DIM * DIM;   // [Wk;Wv]
        const float* bias = in_proj_b + DIM;
        const int wave = tid >> 6, lane = tid & 63;
        const int lr = tid >> 2, lc = (tid & 3) * 8;
        const int fr = lane & 15, fk = (lane >> 4) * 8;

        floatx4 acc[4];
#pragma unroll
        for (int i = 0; i < 4; ++i) acc[i] = (floatx4){0.f, 0.f, 0.f, 0.f};
        for (int k0 = 0; k0 < DIM; k0 += 32) {
            short8 av = ld8(hdr + (size_t)(m0 + lr) * DIM + k0 + lc);
            short8 wv = ld8(W   + (size_t)(n0 + lr) * DIM + k0 + lc);
            __syncthreads();
            *reinterpret_cast<short8*>(&As[lr * 40 + lc]) = av;
            *reinterpret_cast<short8*>(&Bs[lr * 40 + lc]) = wv;
            __syncthreads();
            short8 af = *reinterpret_cast<const short8*>(&As[(wave * 16 + fr) * 40 + fk]);
#pragma unroll
            for (int t = 0; t < 4; ++t) {
                short8 bfv = *reinterpret_cast<const short8*>(&Bs[(t * 16 + fr) * 40 + fk]);
                acc[t] = __builtin_amdgcn_mfma_f32_16x16x32_bf16(af, bfv, acc[t], 0, 0, 0);
            }
        }
        const int col_l = lane & 15, row_q = (lane >> 4) * 4;
#pragma unroll
        for (int t = 0; t < 4; ++t) {
            const int col = n0 + t * 16 + col_l;
            const float bv = bias[col];
#pragma unroll
            for (int r = 0; r < 4; ++r) {
                const int row = m0 + wave * 16 + row_q + r;
                HKV[(size_t)row * 1536 + col] = __float2bfloat16(acc[t][r] + bv);
            }
        }
    }
}

// ---------------------------------------------------------------------------
// Vectorized attention, 2 cells per 256-thr block (half-block per cell).
// All q/HKV/ctx traffic as short8 (16 B). ctx -> ws (bf16).
// ---------------------------------------------------------------------------
__global__ __launch_bounds__(256) void attn_v_kernel(
    const bf16* __restrict__ q, bf16* __restrict__ ctx,
    const bf16* __restrict__ HKV, const int* __restrict__ map,
    float* __restrict__ wout)
{
    const int h = threadIdx.x >> 7;           // half-block 0/1
    const int t = threadIdx.x & 127;          // lane within half
    const int cell = blockIdx.x * 2 + h;
    __shared__ float qs[2][DIM];
    __shared__ float sc[2][64];
    __shared__ float at[2][64];
    __shared__ int   ids[2][MAXH];
    __shared__ float msk[2][MAXH];

    if (t < MAXH) {
        int id = map[cell * MAXH + t];
        msk[h][t] = (id >= 0) ? 1.f : 0.f;
        ids[h][t] = (id >= 0) ? id : 0;
    }
    if (t < 96) {  // stage q: 96 x short8
        short8 qv = *reinterpret_cast<const short8*>((const short*)q + (size_t)cell * DIM + t * 8);
#pragma unroll
        for (int e = 0; e < 8; ++e) qs[h][t * 8 + e] = b2f(qv[e]);
    }
    __syncthreads();

    if (t < 64) {  // scores: head a = t>>3, slot j = t&7
        const int a = t >> 3, j = t & 7;
        const short* kp = (const short*)HKV + (size_t)ids[h][j] * 1536 + a * DHEAD;
        float s = 0.f;
#pragma unroll
        for (int c = 0; c < 12; ++c) {
            short8 kv = *reinterpret_cast<const short8*>(kp + c * 8);
#pragma unroll
            for (int e = 0; e < 8; ++e)
                s += qs[h][a * DHEAD + c * 8 + e] * b2f(kv[e]);
        }
        s *= 0.10206207261596577f;  // 1/sqrt(96)
        sc[h][t] = (msk[h][j] != 0.f) ? s : -1e9f;
    }
    __syncthreads();

    if (t < NHEADS) {  // softmax per head
        float m = -3e38f;
        for (int j = 0; j < MAXH; ++j) m = fmaxf(m, sc[h][t * 8 + j]);
        float e[MAXH]; float sum = 0.f;
        for (int j = 0; j < MAXH; ++j) { e[j] = expf(sc[h][t * 8 + j] - m); sum += e[j]; }
        const float inv = 1.f / sum;
        for (int j = 0; j < MAXH; ++j)
            at[h][t * 8 + j] = (msk[h][j] != 0.f) ? e[j] * inv : 0.f;
    }
    __syncthreads();

    if (t < MAXH) {  // head-averaged weights
        float s = 0.f;
        for (int a = 0; a < NHEADS; ++a) s += at[h][a * 8 + t];
        wout[(size_t)cell * MAXH + t] = s * 0.125f;
    }

    if (t < 96) {  // ctx: dims [t*8, t*8+8), head a = t/12
        const int a = t / 12, d0 = t * 8;
        float acc[8];
#pragma unroll
        for (int e = 0; e < 8; ++e) acc[e] = 0.f;
#pragma unroll
        for (int j = 0; j < MAXH; ++j) {
            short8 vv = *reinterpret_cast<const short8*>(
                (const short*)HKV + (size_t)ids[h][j] * 1536 + DIM + d0);
            const float w = at[h][a * 8 + j];
#pragma unroll
            for (int e = 0; e < 8; ++e) acc[e] += w * b2f(vv[e]);
        }
        short8 o;
#pragma unroll
        for (int e = 0; e < 8; ++e) o[e] = f2b(acc[e]);
        *reinterpret_cast<short8*>((short*)ctx + (size_t)cell * DIM + d0) = o;
    }
}

// ---------------------------------------------------------------------------
// LayerNorm + ReLU + has-select, IN-PLACE, vectorized; 2 cells per 384-thr
// block (three waves per cell; halves wave-aligned: 192 = 3 x 64).
// ---------------------------------------------------------------------------
__global__ __launch_bounds__(384) void ln_v_kernel(
    float* io, const int* __restrict__ map,
    const float* __restrict__ ce, const int* __restrict__ pos,
    const float* __restrict__ re, const float* __restrict__ co,
    const float* __restrict__ g, const float* __restrict__ b)
{
    const int h = threadIdx.x / 192;          // half 0/1
    const int t = threadIdx.x % 192;
    const int cell = blockIdx.x * 2 + h;
    const int wave = t >> 6, lane = t & 63;
    __shared__ float ws_[2][3], wq_[2][3];
    __shared__ int hasf[2];
    if (threadIdx.x < 2) hasf[threadIdx.x] = 0;

    float* hp = io + (size_t)cell * DIM;
    floatx4 v = *reinterpret_cast<const floatx4*>(hp + t * 4);
    float s  = v[0] + v[1] + v[2] + v[3];
    float q2 = v[0]*v[0] + v[1]*v[1] + v[2]*v[2] + v[3]*v[3];
#pragma unroll
    for (int off = 32; off > 0; off >>= 1) {
        s  += __shfl_down(s, off);
        q2 += __shfl_down(q2, off);
    }
    __syncthreads();           // hasf init visible
    if (t < MAXH && map[cell * MAXH + t] >= 0) hasf[h] = 1;
    if (lane == 0) { ws_[h][wave] = s; wq_[h][wave] = q2; }
    __syncthreads();

    const float mu  = (ws_[h][0] + ws_[h][1] + ws_[h][2]) * (1.f / 768.f);
    const float var = (wq_[h][0] + wq_[h][1] + wq_[h][2]) * (1.f / 768.f) - mu * mu;
    const float inv = rsqrtf(var + 1e-5f);

    if (hasf[h]) {
        floatx4 gv = *reinterpret_cast<const floatx4*>(g + t * 4);
        floatx4 bv = *reinterpret_cast<const floatx4*>(b + t * 4);
        floatx4 o;
#pragma unroll
        for (int e = 0; e < 4; ++e)
            o[e] = fmaxf((v[e] - mu) * inv * gv[e] + bv[e], 0.f);
        *reinterpret_cast<floatx4*>(hp + t * 4) = o;
    } else {
        int pr = pos[cell * 2 + 0]; pr = min(max(pr, 0), 99);
        int pc = pos[cell * 2 + 1]; pc = min(max(pc, 0), 99);
        floatx4 a0 = *reinterpret_cast<const floatx4*>(ce + (size_t)cell * DIM + t * 4);
        floatx4 b0 = *reinterpret_cast<const floatx4*>(re + (size_t)pr * DIM + t * 4);
        floatx4 c0 = *reinterpret_cast<const floatx4*>(co + (size_t)pc * DIM + t * 4);
        floatx4 o;
#pragma unroll
        for (int e = 0; e < 4; ++e) o[e] = a0[e] + b0[e] + c0[e];
        *reinterpret_cast<floatx4*>(hp + t * 4) = o;
    }
}

// ---------------------------------------------------------------------------
extern "C" void kernel_launch(void* const* d_in, const int* in_sizes, int n_in,
                              void* d_out, int out_size, void* d_ws, size_t ws_size,
                              hipStream_t stream) {
    (void)in_sizes; (void)n_in; (void)out_size; (void)ws_size;

    const float* cell_emb  = (const float*)d_in[0];
    const float* hdr_emb   = (const float*)d_in[1];
    const int*   map       = (const int*)d_in[2];
    const int*   pos       = (const int*)d_in[3];
    const float* in_proj_w = (const float*)d_in[4];   // [2304, 768]
    const float* in_proj_b = (const float*)d_in[5];
    const float* out_w     = (const float*)d_in[6];   // [768, 768]
    const float* out_b     = (const float*)d_in[7];
    const float* row_emb   = (const float*)d_in[8];
    const float* col_emb   = (const float*)d_in[9];
    const float* fus_w     = (const float*)d_in[10];  // [768, 1536]
    const float* fus_b     = (const float*)d_in[11];
    const float* ln_g      = (const float*)d_in[12];
    const float* ln_b      = (const float*)d_in[13];
    float* out = (float*)d_out;

    // ws layout (bytes) — total 55,446,528 (ws >= 56.6 MB proven R6-R10):
    //   HKV   bf16 [512,1536]  @ 0          ( 1,572,864)
    //   ctx_b bf16 [16384,768] @ 1572864    (25,165,824)
    //   cwp_b bf16 [16384,768] @ 26738688   (25,165,824)
    //   Wq_b  bf16 [768,768]   @ 51904512   ( 1,179,648)
    //   W_cat bf16 [768,1536]  @ 53084160   ( 2,359,296)  = [W1 | Wc]
    //   biasp f32  [768]       @ 55443456   (      3,072)
    char* ws = (char*)d_ws;
    bf16*  HKV   = (bf16*)ws;
    bf16*  ctx_b = (bf16*)(ws + 1572864);
    bf16*  cwp_b = (bf16*)(ws + 26738688);
    bf16*  Wq_b  = (bf16*)(ws + 51904512);
    bf16*  W_cat = (bf16*)(ws + 53084160);
    float* biasp = (float*)(ws + 55443456);
    // d_out raw-byte scratch: q_b bf16 @ [0, 25165824)  (dead before fusion)
    bf16*  q_b   = (bf16*)d_out;

    // 1. PREP (slow blocks first): Wc, bias', cwp_b, Wq_b, W_cat[:,0:768], HKV
    prep_kernel<<<7633, 256, 0, stream>>>(
        cell_emb, pos, row_emb, col_emb, cwp_b,
        in_proj_w, Wq_b, fus_w, W_cat, out_w, out_b, fus_b, biasp,
        hdr_emb, in_proj_b, HKV);

    // 2. q_b = cwp_b @ Wq_b^T + bq  (bf16 out -> d_out bytes [0,25MB))
    gemm_bf<0, 1><<<768, 256, 0, stream>>>(
        cwp_b, nullptr, Wq_b, DIM, in_proj_b, nullptr, q_b, DIM);

    // 3. attention: q_b -> ctx_b (ws); weights -> d_out tail (fp32)
    attn_v_kernel<<<NCELLS / 2, 256, 0, stream>>>(q_b, ctx_b, HKV, map, out + ND);

    // 4. h = [cwp_b | ctx_b] @ W_cat^T + bias'  (fp32 -> d_out; q_b dead)
    gemm_bf<1, 0><<<768, 256, 0, stream>>>(
        cwp_b, ctx_b, W_cat, 1536, biasp, out, nullptr, 1536);

    // 5. LayerNorm + ReLU + select (in-place on d_out fp32)
    ln_v_kernel<<<NCELLS / 2, 384, 0, stream>>>(out, map, cell_emb, pos,
                                                row_emb, col_emb, ln_g, ln_b);
}